// Round 1
// baseline (389.069 us; speedup 1.0000x reference)
//
#include <hip/hip_runtime.h>

typedef float f32x4 __attribute__((ext_vector_type(4)));
typedef long i64;

#define KDIM 512
#define NDIM 512
#define LDS_STRIDE 520   // A-tile: 512 + 8B pad -> row-to-row bank offset 2 -> conflict-free b64 reads

__device__ __forceinline__ float clamp448(float v) {
    return fminf(fmaxf(v, -448.0f), 448.0f);
}

// ---------------- Kernel 1: per-block partial abs-max (NO atomics) --------------------------
// Blocks 0..4095 cover x, 4096..4127 cover w. The previous version ended with 4128
// device-scope atomicMax ops to two words in one cache line -> memory-side serialization
// tail. Now each block stores its partial to a contention-free scratch slot.
__global__ __launch_bounds__(256) void amax_kernel(const float4* __restrict__ x,
                                                   const float4* __restrict__ w,
                                                   float* __restrict__ partial) {
    const int tid = threadIdx.x;
    float m = 0.0f;
    if (blockIdx.x < 4096) {
        int base = blockIdx.x * 256 + tid;
        #pragma unroll
        for (int j = 0; j < 8; ++j) {
            float4 v = x[base + j * 1048576];
            m = fmaxf(m, fmaxf(fmaxf(fabsf(v.x), fabsf(v.y)), fmaxf(fabsf(v.z), fabsf(v.w))));
        }
    } else {
        int base = (blockIdx.x - 4096) * 256 + tid;
        #pragma unroll
        for (int j = 0; j < 8; ++j) {
            float4 v = w[base + j * 8192];
            m = fmaxf(m, fmaxf(fmaxf(fabsf(v.x), fabsf(v.y)), fmaxf(fabsf(v.z), fabsf(v.w))));
        }
    }
    #pragma unroll
    for (int off = 32; off > 0; off >>= 1)
        m = fmaxf(m, __shfl_down(m, off, 64));
    __shared__ float red[4];
    const int wave = tid >> 6, lane = tid & 63;
    if (lane == 0) red[wave] = m;
    __syncthreads();
    if (tid == 0)
        partial[blockIdx.x] = fmaxf(fmaxf(red[0], red[1]), fmaxf(red[2], red[3]));
}

// ---------------- Kernel 1b: single-block finalize -> scales[0]=x_amax, scales[1]=w_amax ----
__global__ __launch_bounds__(256) void reduce_kernel(const float* __restrict__ partial,
                                                     float* __restrict__ scales) {
    const int tid = threadIdx.x;
    float mx = 0.0f, mw = 0.0f;
    #pragma unroll
    for (int j = 0; j < 16; ++j)
        mx = fmaxf(mx, partial[j * 256 + tid]);
    if (tid < 32) mw = partial[4096 + tid];
    #pragma unroll
    for (int off = 32; off > 0; off >>= 1) {
        mx = fmaxf(mx, __shfl_down(mx, off, 64));
        mw = fmaxf(mw, __shfl_down(mw, off, 64));
    }
    __shared__ float red[8];
    const int wave = tid >> 6, lane = tid & 63;
    if (lane == 0) { red[wave] = mx; red[4 + wave] = mw; }
    __syncthreads();
    if (tid == 0) {
        scales[0] = fmaxf(fmaxf(red[0], red[1]), fmaxf(red[2], red[3]));
        scales[1] = fmaxf(fmaxf(red[4], red[5]), fmaxf(red[6], red[7]));
    }
}

// ---------------- Kernel 2: quantize weight [K,N] fp32 -> w_fp8 [N,K] e4m3 ------------------
// Coalesced float4 reads of w (1 MB fetched exactly once); byte-scatter writes land in L2
// (wq is 256 KB, L2-resident for the gemm).
__global__ __launch_bounds__(256) void wquant_kernel(const float4* __restrict__ wv,
                                                     const float* __restrict__ scales,
                                                     unsigned char* __restrict__ wq) {
    const float ws = 448.0f / fmaxf(scales[1], 1e-12f);
    #pragma unroll
    for (int j = 0; j < 4; ++j) {
        const int idx = blockIdx.x * 1024 + j * 256 + threadIdx.x;  // 65,536 float4 total
        const int k = idx >> 7;          // w row (K), 128 float4 per row
        const int n4 = idx & 127;        // float4 within row
        float4 v = wv[idx];
        float a[4] = {v.x, v.y, v.z, v.w};
        #pragma unroll
        for (int i = 0; i < 4; ++i) {
            float q = clamp448(a[i] * ws);
            int p = __builtin_amdgcn_cvt_pk_fp8_f32(q, q, 0, false);
            wq[(n4 * 4 + i) * KDIM + k] = (unsigned char)(p & 0xff);
        }
    }
}

// ---------------- Kernel 3: fused x-quant (LDS staging) + fp8 MFMA GEMM + dequant ------------
// Block: 64 rows x full K=512. 4 waves, each 64x64 output per n-chunk, 2 chunks of 256 cols.
// Epilogue now stores DIRECT from accumulators: the C/D layout (col = lane&15) makes each
// quarter-wave's store a full 64 B line, so staging through LDS bought nothing and cost
// 16.6 KB LDS (occupancy 3 -> 4 blocks/CU) plus 16 __syncthreads per block (now: 1).
__global__ __launch_bounds__(256, 4) void gemm_kernel(const float* __restrict__ x,
                                                      const unsigned char* __restrict__ wq,
                                                      const float* __restrict__ scales,
                                                      float* __restrict__ out) {
    __shared__ unsigned char lds_a[64 * LDS_STRIDE];  // 33,280 B -> 4 blocks/CU
    const int tid = threadIdx.x;
    const long m0 = (long)blockIdx.x * 64;

    const float ax = fmaxf(scales[0], 1e-12f);
    const float aw = fmaxf(scales[1], 1e-12f);
    const float xs = 448.0f / ax;
    const float ws = 448.0f / aw;
    const float inv = (1.0f / xs) * (1.0f / ws);   // mirror reference dequant arithmetic

    // ---- stage: 64x512 fp32 -> fp8 into LDS (8,192 float4, 32 per thread, coalesced) ----
    const float4* xv = (const float4*)(x + m0 * KDIM);
    #pragma unroll 8
    for (int j = 0; j < 32; ++j) {
        int f4i = tid + 256 * j;
        float4 v = xv[f4i];
        int row = f4i >> 7;             // 128 float4 per row
        int colb = (f4i & 127) << 2;    // byte column
        float a0 = clamp448(v.x * xs);
        float a1 = clamp448(v.y * xs);
        float a2 = clamp448(v.z * xs);
        float a3 = clamp448(v.w * xs);
        int p = __builtin_amdgcn_cvt_pk_fp8_f32(a0, a1, 0, false);
        p = __builtin_amdgcn_cvt_pk_fp8_f32(a2, a3, p, true);
        *(unsigned*)&lds_a[row * LDS_STRIDE + colb] = (unsigned)p;
    }
    __syncthreads();   // the ONLY barrier in this kernel

    const int wave = tid >> 6, lane = tid & 63;
    const int ln = lane & 15, lg = lane >> 4;
    const int kofs = lg * 8;
    float* outp = out + m0 * NDIM;

    for (int chunk = 0; chunk < 2; ++chunk) {
        const int nbase = chunk * 256 + wave * 64;
        f32x4 acc[4][4];
        #pragma unroll
        for (int a = 0; a < 4; ++a)
            #pragma unroll
            for (int b = 0; b < 4; ++b)
                acc[a][b] = (f32x4){0.0f, 0.0f, 0.0f, 0.0f};

        for (int ks = 0; ks < 16; ++ks) {
            const int kb = ks * 32 + kofs;
            i64 af[4], bf[4];
            #pragma unroll
            for (int t = 0; t < 4; ++t)
                af[t] = *(const i64*)&lds_a[(t * 16 + ln) * LDS_STRIDE + kb];
            #pragma unroll
            for (int t = 0; t < 4; ++t)
                bf[t] = *(const i64*)&wq[(nbase + t * 16 + ln) * KDIM + kb];
            #pragma unroll
            for (int tm = 0; tm < 4; ++tm)
                #pragma unroll
                for (int tn = 0; tn < 4; ++tn)
                    acc[tm][tn] = __builtin_amdgcn_mfma_f32_16x16x32_fp8_fp8(
                        af[tm], bf[tn], acc[tm][tn], 0, 0, 0);
        }

        // ---- epilogue: direct stores. MFMA C/D layout: col = lane&15, row = (lane>>4)*4+reg.
        // Each quarter-wave (ln = 0..15) writes 16 consecutive floats = one full 64 B line.
        #pragma unroll
        for (int tm = 0; tm < 4; ++tm) {
            #pragma unroll
            for (int tn = 0; tn < 4; ++tn) {
                const int c = nbase + tn * 16 + ln;
                #pragma unroll
                for (int r = 0; r < 4; ++r)
                    outp[(long)(tm * 16 + lg * 4 + r) * NDIM + c] = acc[tm][tn][r] * inv;
            }
        }
    }
}

extern "C" void kernel_launch(void* const* d_in, const int* in_sizes, int n_in,
                              void* d_out, int out_size, void* d_ws, size_t ws_size,
                              hipStream_t stream) {
    const float* x = (const float*)d_in[0];
    const float* w = (const float*)d_in[1];
    float* out = (float*)d_out;
    float* scales = (float*)d_ws;                                   // ws[0]=x_amax, ws[1]=w_amax
    unsigned char* wq = (unsigned char*)d_ws + 256;                 // 262,144 B fp8 weight [N,K]
    float* partial = (float*)((char*)d_ws + 256 + 262144);          // 4128 floats partial maxes
    const int M = in_sizes[0] / KDIM;                               // 65536

    // no memset needed: partial[] fully written by amax, scales fully written by reduce
    amax_kernel<<<4096 + 32, 256, 0, stream>>>((const float4*)x, (const float4*)w, partial);
    reduce_kernel<<<1, 256, 0, stream>>>(partial, scales);
    wquant_kernel<<<64, 256, 0, stream>>>((const float4*)w, scales, wq);
    gemm_kernel<<<M / 64, 256, 0, stream>>>(x, wq, scales, out);
}